// Round 5
// baseline (247.005 us; speedup 1.0000x reference)
//
#include <hip/hip_runtime.h>
#include <stdint.h>

#define B_ 2
#define S_ 2048
#define D_ 1024
#define H_ 16
#define DH_ 64
#define M_ 4096  // B_*S_

typedef unsigned short u16;
typedef unsigned int u32;
typedef short mfma_elem_t;
typedef mfma_elem_t bfrag8 __attribute__((ext_vector_type(8)));
typedef float floatx4 __attribute__((ext_vector_type(4)));

__device__ __forceinline__ u16 f2bf(float f) {
  unsigned u = __float_as_uint(f);
  u += 0x7fff + ((u >> 16) & 1);  // RNE
  return (u16)(u >> 16);
}

// pack two positive floats to packed bf16 (round-half-up)
__device__ __forceinline__ u32 pack_bf16(float a, float b) {
  u32 ua = __float_as_uint(a) + 0x8000u;
  u32 ub = __float_as_uint(b) + 0x8000u;
#if __has_builtin(__builtin_amdgcn_perm)
  return __builtin_amdgcn_perm(ub, ua, 0x07060302u);
#else
  return (ua >> 16) | (ub & 0xffff0000u);
#endif
}

__device__ __forceinline__ void gl_lds16(const void* g, void* l) {
  __builtin_amdgcn_global_load_lds(
      (__attribute__((address_space(1))) void*)(g),
      (__attribute__((address_space(3))) void*)(l), 16, 0, 0);
}

// ---------------- convert inputs fp32 -> bf16 ----------------
__global__ __launch_bounds__(256) void k_convert_x(
    const float* __restrict__ q, const float* __restrict__ k, const float* __restrict__ v,
    u16* __restrict__ xq, u16* __restrict__ xk, u16* __restrict__ xv) {
  const float* src = blockIdx.z == 0 ? q : (blockIdx.z == 1 ? k : v);
  u16* dst = blockIdx.z == 0 ? xq : (blockIdx.z == 1 ? xk : xv);
  int i = (blockIdx.x * 256 + threadIdx.x) * 4;
  float4 f = *(const float4*)(src + i);
  ushort4 o;
  o.x = f2bf(f.x); o.y = f2bf(f.y); o.z = f2bf(f.z); o.w = f2bf(f.w);
  *(ushort4*)(dst + i) = o;
}

// ---------------- convert + transpose W fp32[1024][1024] -> bf16 W^T ----------------
__global__ __launch_bounds__(256) void k_convert_w(
    const float* __restrict__ wq, const float* __restrict__ wk,
    const float* __restrict__ wv, const float* __restrict__ wo,
    u16* __restrict__ tq, u16* __restrict__ tk, u16* __restrict__ tv, u16* __restrict__ to_) {
  const int gz = blockIdx.z;
  const float* w = gz == 0 ? wq : gz == 1 ? wk : gz == 2 ? wv : wo;
  u16* t = gz == 0 ? tq : gz == 1 ? tk : gz == 2 ? tv : to_;
  __shared__ float tile[32][33];
  int r0 = blockIdx.y * 32, c0 = blockIdx.x * 32;
  int tx = threadIdx.x, ty = threadIdx.y;
#pragma unroll
  for (int i = 0; i < 4; i++) {
    int r = ty + i * 8;
    tile[r][tx] = w[(size_t)(r0 + r) * D_ + c0 + tx];
  }
  __syncthreads();
#pragma unroll
  for (int i = 0; i < 4; i++) {
    int r = ty + i * 8;
    t[(size_t)(c0 + r) * D_ + r0 + tx] = f2bf(tile[tx][r]);
  }
}

// ---------------- fused QKV projection GEMM (dbuf, 1 barrier/iter) ----------------
// Q out scaled by 0.125*log2e (folded softmax scale); Q,K out: [B,H,S,DH];
// V out: [B,H,DH,S] (transposed in epilogue)
__global__ __launch_bounds__(256, 3) void k_gemm_qkv(
    const u16* __restrict__ xq, const u16* __restrict__ xk, const u16* __restrict__ xv,
    const u16* __restrict__ wtq, const u16* __restrict__ wtk, const u16* __restrict__ wtv,
    const float* __restrict__ bq, const float* __restrict__ bk, const float* __restrict__ bv,
    u16* __restrict__ oq, u16* __restrict__ ok, u16* __restrict__ ovt) {
  const int gz = blockIdx.z;
  const u16* X = gz == 0 ? xq : gz == 1 ? xk : xv;
  const u16* WT = gz == 0 ? wtq : gz == 1 ? wtk : wtv;
  const float* bias = gz == 0 ? bq : gz == 1 ? bk : bv;
  u16* outsd = gz == 0 ? oq : ok;
  const float qscale = gz == 0 ? 0.125f * 1.4426950408889634f : 1.0f;

  __shared__ u16 sbuf[2][8192];

  const int t = threadIdx.x;
  const int w = t >> 6, lane = t & 63, l15 = lane & 15, quad = lane >> 4;
  const int wm = (w >> 1) * 64, wn = (w & 1) * 64;
  const int m0 = blockIdx.y * 128, n0 = blockIdx.x * 128;

  floatx4 acc[4][4];
  floatx4 zero = {0.f, 0.f, 0.f, 0.f};
#pragma unroll
  for (int mt = 0; mt < 4; mt++)
#pragma unroll
    for (int nt = 0; nt < 4; nt++) acc[mt][nt] = zero;

  auto stage = [&](int kt, int b) {
    int k0 = kt * 32;
#pragma unroll
    for (int i = 0; i < 2; i++) {
      int chunk = i * 256 + t;
      gl_lds16(X + (size_t)(m0 + (chunk >> 2)) * D_ + k0 + (chunk & 3) * 8,
               sbuf[b] + i * 2048 + w * 512);
      gl_lds16(WT + (size_t)(n0 + (chunk >> 2)) * D_ + k0 + (chunk & 3) * 8,
               sbuf[b] + 4096 + i * 2048 + w * 512);
    }
  };

  stage(0, 0);
  for (int kt = 0; kt < 32; kt++) {
    __syncthreads();
    if (kt < 31) stage(kt + 1, (kt + 1) & 1);
    const u16* As = sbuf[kt & 1];
    const u16* Bs = sbuf[kt & 1] + 4096;
    bfrag8 af[4], bf[4];
#pragma unroll
    for (int mt = 0; mt < 4; mt++)
      af[mt] = *(const bfrag8*)(As + (wm + mt * 16 + l15) * 32 + quad * 8);
#pragma unroll
    for (int nt = 0; nt < 4; nt++)
      bf[nt] = *(const bfrag8*)(Bs + (wn + nt * 16 + l15) * 32 + quad * 8);
#pragma unroll
    for (int mt = 0; mt < 4; mt++)
#pragma unroll
      for (int nt = 0; nt < 4; nt++)
        acc[mt][nt] = __builtin_amdgcn_mfma_f32_16x16x32_bf16(af[mt], bf[nt], acc[mt][nt], 0, 0, 0);
  }

  if (gz < 2) {
#pragma unroll
    for (int mt = 0; mt < 4; mt++)
#pragma unroll
      for (int nt = 0; nt < 4; nt++) {
        int Nc = n0 + wn + nt * 16 + l15;
        float bv_ = bias[Nc];
        int hh = Nc >> 6, dh = Nc & 63;
#pragma unroll
        for (int r = 0; r < 4; r++) {
          int Mr = m0 + wm + mt * 16 + quad * 4 + r;
          int bb = Mr >> 11, ss = Mr & 2047;
          outsd[((size_t)(bb * H_ + hh) * S_ + ss) * DH_ + dh] =
              f2bf((acc[mt][nt][r] + bv_) * qscale);
        }
      }
  } else {
#pragma unroll
    for (int mt = 0; mt < 4; mt++)
#pragma unroll
      for (int nt = 0; nt < 4; nt++) {
        int Nc = n0 + wn + nt * 16 + l15;
        float bv_ = bias[Nc];
        int hh = Nc >> 6, dh = Nc & 63;
        int Mr0 = m0 + wm + mt * 16 + quad * 4;
        int bb = Mr0 >> 11, ss0 = Mr0 & 2047;
        ushort4 o;
        o.x = f2bf(acc[mt][nt][0] + bv_);
        o.y = f2bf(acc[mt][nt][1] + bv_);
        o.z = f2bf(acc[mt][nt][2] + bv_);
        o.w = f2bf(acc[mt][nt][3] + bv_);
        *(ushort4*)(ovt + ((size_t)(bb * H_ + hh) * DH_ + dh) * S_ + ss0) = o;
      }
  }
}

// ---------------- final GEMM (dbuf): out fp32 = O[4096,1024] * Wo + bo ----------------
__global__ __launch_bounds__(256, 3) void k_gemm_final(
    const u16* __restrict__ X, const u16* __restrict__ WT,
    const float* __restrict__ bias, float* __restrict__ out) {
  __shared__ u16 sbuf[2][8192];
  const int t = threadIdx.x;
  const int w = t >> 6, lane = t & 63, l15 = lane & 15, quad = lane >> 4;
  const int wm = (w >> 1) * 64, wn = (w & 1) * 64;
  const int m0 = blockIdx.y * 128, n0 = blockIdx.x * 128;

  floatx4 acc[4][4];
  floatx4 zero = {0.f, 0.f, 0.f, 0.f};
#pragma unroll
  for (int mt = 0; mt < 4; mt++)
#pragma unroll
    for (int nt = 0; nt < 4; nt++) acc[mt][nt] = zero;

  auto stage = [&](int kt, int b) {
    int k0 = kt * 32;
#pragma unroll
    for (int i = 0; i < 2; i++) {
      int chunk = i * 256 + t;
      gl_lds16(X + (size_t)(m0 + (chunk >> 2)) * D_ + k0 + (chunk & 3) * 8,
               sbuf[b] + i * 2048 + w * 512);
      gl_lds16(WT + (size_t)(n0 + (chunk >> 2)) * D_ + k0 + (chunk & 3) * 8,
               sbuf[b] + 4096 + i * 2048 + w * 512);
    }
  };

  stage(0, 0);
  for (int kt = 0; kt < 32; kt++) {
    __syncthreads();
    if (kt < 31) stage(kt + 1, (kt + 1) & 1);
    const u16* As = sbuf[kt & 1];
    const u16* Bs = sbuf[kt & 1] + 4096;
    bfrag8 af[4], bf[4];
#pragma unroll
    for (int mt = 0; mt < 4; mt++)
      af[mt] = *(const bfrag8*)(As + (wm + mt * 16 + l15) * 32 + quad * 8);
#pragma unroll
    for (int nt = 0; nt < 4; nt++)
      bf[nt] = *(const bfrag8*)(Bs + (wn + nt * 16 + l15) * 32 + quad * 8);
#pragma unroll
    for (int mt = 0; mt < 4; mt++)
#pragma unroll
      for (int nt = 0; nt < 4; nt++)
        acc[mt][nt] = __builtin_amdgcn_mfma_f32_16x16x32_bf16(af[mt], bf[nt], acc[mt][nt], 0, 0, 0);
  }
#pragma unroll
  for (int mt = 0; mt < 4; mt++)
#pragma unroll
    for (int nt = 0; nt < 4; nt++) {
      int Nc = n0 + wn + nt * 16 + l15;
      float bv_ = bias[Nc];
#pragma unroll
      for (int r = 0; r < 4; r++) {
        int Mr = m0 + wm + mt * 16 + quad * 4 + r;
        out[(size_t)Mr * D_ + Nc] = acc[mt][nt][r] + bv_;
      }
    }
}

// ---------------- flash attention v5: 2q x 2kv wave split + dbuf ----------------
// Block: 128 q; staged kv-tile 64 (16 KB), double-buffered, 1 barrier/iter
// (stage(kt+1) issued after barrier, in flight across full compute phase).
// Wave tile: 64 q x 32 kv. Q pre-scaled by 0.125*log2e -> p = exp2(s).
// LDS (u16): buf b @ b*8192: K [2 dh-half][64 kv][32] @+0, V [2 kv-half][64 dh][32] @+4096
//            P per wave @16384 + w*2304: [64 q][stride 36].
// Epilogue: waves (w, w^1) share q rows, hold kv-half partials -> LDS combine.
__global__ __launch_bounds__(256, 2) void k_attn(
    const u16* __restrict__ Q, const u16* __restrict__ K,
    const u16* __restrict__ Vt, u16* __restrict__ O) {
  __shared__ u16 lds[25600];  // 50 KB

  const int t = threadIdx.x, w = t >> 6, lane = t & 63, l15 = lane & 15, quad = lane >> 4;
  const int bh = blockIdx.z * H_ + blockIdx.y;
  const int q0 = blockIdx.x * 128;
  const int qh = (w >> 1) * 64;  // wave's q-half
  const int kvh = w & 1;         // wave's kv-half index (32-wide)
  const u16* Qb = Q + (size_t)bh * S_ * DH_;
  const u16* Kb = K + (size_t)bh * S_ * DH_;
  const u16* Vb = Vt + (size_t)bh * DH_ * S_;
  u16* Pw = lds + 16384 + w * 2304;

  bfrag8 qf[4][2];  // B-operand [n=q][k=dh], loaded once from global
#pragma unroll
  for (int qt = 0; qt < 4; qt++)
#pragma unroll
    for (int ks = 0; ks < 2; ks++)
      qf[qt][ks] = *(const bfrag8*)(Qb + (size_t)(q0 + qh + qt * 16 + l15) * DH_ + ks * 32 + quad * 8);

  auto stage = [&](int kv0, int b) {
    u16* Kbuf = lds + b * 8192;
    u16* Vbuf = lds + b * 8192 + 4096;
#pragma unroll
    for (int ks = 0; ks < 2; ks++)
      gl_lds16(Kb + (size_t)(kv0 + (t >> 2)) * DH_ + ks * 32 + (t & 3) * 8,
               Kbuf + ks * 2048 + w * 512);
#pragma unroll
    for (int ksp = 0; ksp < 2; ksp++)
      gl_lds16(Vb + (size_t)(t >> 2) * S_ + kv0 + ksp * 32 + (t & 3) * 8,
               Vbuf + ksp * 2048 + w * 512);
  };

  floatx4 oacc[4][4];
  float lrow[4] = {0.f, 0.f, 0.f, 0.f};
  floatx4 zero = {0.f, 0.f, 0.f, 0.f};
#pragma unroll
  for (int qt = 0; qt < 4; qt++)
#pragma unroll
    for (int dt = 0; dt < 4; dt++) oacc[qt][dt] = zero;

  stage(0, 0);
  for (int kt = 0; kt < 32; kt++) {
    __syncthreads();  // drains stage(kt); all waves done reading buf[(kt+1)&1]
    if (kt < 31) stage((kt + 1) * 64, (kt + 1) & 1);
    const u16* Kbuf = lds + (kt & 1) * 8192;
    const u16* Vbuf = lds + (kt & 1) * 8192 + 4096;

    // S^T: D[m=kv][n=q] = mfma(A=K-frag, B=Q-frag); wave's kv rows = kvh*32 + nt*16
    floatx4 sacc[2][4];
#pragma unroll
    for (int nt = 0; nt < 2; nt++) {
      bfrag8 kf0 = *(const bfrag8*)(Kbuf + (kvh * 32 + nt * 16 + l15) * 32 + quad * 8);
      bfrag8 kf1 = *(const bfrag8*)(Kbuf + 2048 + (kvh * 32 + nt * 16 + l15) * 32 + quad * 8);
#pragma unroll
      for (int qt = 0; qt < 4; qt++) {
        floatx4 s0 = __builtin_amdgcn_mfma_f32_16x16x32_bf16(kf0, qf[qt][0], zero, 0, 0, 0);
        sacc[nt][qt] = __builtin_amdgcn_mfma_f32_16x16x32_bf16(kf1, qf[qt][1], s0, 0, 0, 0);
      }
    }

    // softmax: p = exp2(s); lane-local l partials; pack; P^T[q][32 kv] to wave-private LDS
#pragma unroll
    for (int nt = 0; nt < 2; nt++)
#pragma unroll
      for (int qt = 0; qt < 4; qt++) {
        float p0 = __builtin_amdgcn_exp2f(sacc[nt][qt][0]);
        float p1 = __builtin_amdgcn_exp2f(sacc[nt][qt][1]);
        float p2 = __builtin_amdgcn_exp2f(sacc[nt][qt][2]);
        float p3 = __builtin_amdgcn_exp2f(sacc[nt][qt][3]);
        lrow[qt] += (p0 + p1) + (p2 + p3);
        uint2 pd;
        pd.x = pack_bf16(p0, p1);
        pd.y = pack_bf16(p2, p3);
        *(uint2*)(Pw + (qt * 16 + l15) * 36 + nt * 16 + quad * 4) = pd;
      }

    // PV: D[m=dh][n=q] += V^T-frag x P-frag (wave's kv-half of V)
    bfrag8 pf[4];
#pragma unroll
    for (int qt = 0; qt < 4; qt++)
      pf[qt] = *(const bfrag8*)(Pw + (qt * 16 + l15) * 36 + quad * 8);
#pragma unroll
    for (int dt = 0; dt < 4; dt++) {
      bfrag8 vf = *(const bfrag8*)(Vbuf + kvh * 2048 + (dt * 16 + l15) * 32 + quad * 8);
#pragma unroll
      for (int qt = 0; qt < 4; qt++)
        oacc[qt][dt] = __builtin_amdgcn_mfma_f32_16x16x32_bf16(vf, pf[qt], oacc[qt][dt], 0, 0, 0);
    }
  }

  // ---- cross-wave combine: waves (w, w^1) share q rows, hold kv-half partials ----
  __syncthreads();  // everyone done with K/V buffers; reuse LDS for combine
  float* ocmb = (float*)lds;         // pair p region: [64 q][stride 68] fp32
  float* lcmb = (float*)lds + 8704;  // l partials: pair p at +p*64
  const int p = w >> 1;

#pragma unroll
  for (int qt = 0; qt < 4; qt++) {
    float l = lrow[qt];
    l += __shfl_xor(l, 16, 64);
    l += __shfl_xor(l, 32, 64);
    lrow[qt] = l;
  }

  if (w & 1) {  // writer wave of the pair
    float* po = ocmb + p * 4352;
#pragma unroll
    for (int qt = 0; qt < 4; qt++) {
#pragma unroll
      for (int dt = 0; dt < 4; dt++)
        *(floatx4*)(po + (qt * 16 + l15) * 68 + dt * 16 + quad * 4) = oacc[qt][dt];
      if (quad == 0) lcmb[p * 64 + qt * 16 + l15] = lrow[qt];
    }
  }
  __syncthreads();
  if (!(w & 1)) {  // reader: sum partials, normalize, store
    float* po = ocmb + p * 4352;
#pragma unroll
    for (int qt = 0; qt < 4; qt++) {
      float rinv = 1.0f / (lrow[qt] + lcmb[p * 64 + qt * 16 + l15]);
      int qrow = q0 + qh + qt * 16 + l15;
#pragma unroll
      for (int dt = 0; dt < 4; dt++) {
        floatx4 oo = oacc[qt][dt] + *(const floatx4*)(po + (qt * 16 + l15) * 68 + dt * 16 + quad * 4);
        ushort4 o;
        o.x = f2bf(oo[0] * rinv);
        o.y = f2bf(oo[1] * rinv);
        o.z = f2bf(oo[2] * rinv);
        o.w = f2bf(oo[3] * rinv);
        *(ushort4*)(O + ((size_t)blockIdx.z * S_ + qrow) * D_ + blockIdx.y * DH_ + dt * 16 + quad * 4) = o;
      }
    }
  }
}

// ---------------- launch ----------------
extern "C" void kernel_launch(void* const* d_in, const int* in_sizes, int n_in,
                              void* d_out, int out_size, void* d_ws, size_t ws_size,
                              hipStream_t stream) {
  const float* queries = (const float*)d_in[0];
  const float* keys = (const float*)d_in[1];
  const float* values = (const float*)d_in[2];
  const float* Wq = (const float*)d_in[3];
  const float* bq = (const float*)d_in[4];
  const float* Wk = (const float*)d_in[5];
  const float* bk = (const float*)d_in[6];
  const float* Wv = (const float*)d_in[7];
  const float* bv = (const float*)d_in[8];
  const float* Wo = (const float*)d_in[9];
  const float* bo = (const float*)d_in[10];

  const size_t NXB = (size_t)M_ * D_ * 2;
  const size_t WB = (size_t)D_ * D_ * 2;
  if (ws_size < 7 * NXB + 4 * WB) return;

  char* ws = (char*)d_ws;
  u16* Xq = (u16*)(ws);
  u16* Xk = (u16*)(ws + NXB);
  u16* Xv = (u16*)(ws + 2 * NXB);
  u16* WqT = (u16*)(ws + 3 * NXB);
  u16* WkT = (u16*)(ws + 3 * NXB + WB);
  u16* WvT = (u16*)(ws + 3 * NXB + 2 * WB);
  u16* WoT = (u16*)(ws + 3 * NXB + 3 * WB);
  char* ws2 = ws + 3 * NXB + 4 * WB;
  u16* Qhs = (u16*)(ws2);
  u16* Khs = (u16*)(ws2 + NXB);
  u16* VtB = (u16*)(ws2 + 2 * NXB);
  u16* Obuf = (u16*)(ws2 + 3 * NXB);
  float* outp = (float*)d_out;

  k_convert_x<<<dim3(4096, 1, 3), 256, 0, stream>>>(queries, keys, values, Xq, Xk, Xv);
  k_convert_w<<<dim3(32, 32, 4), dim3(32, 8), 0, stream>>>(Wq, Wk, Wv, Wo, WqT, WkT, WvT, WoT);
  k_gemm_qkv<<<dim3(8, 32, 3), 256, 0, stream>>>(Xq, Xk, Xv, WqT, WkT, WvT, bq, bk, bv, Qhs, Khs, VtB);
  k_attn<<<dim3(16, 16, 2), 256, 0, stream>>>(Qhs, Khs, VtB, Obuf);
  k_gemm_final<<<dim3(8, 32), 256, 0, stream>>>(Obuf, WoT, bo, outp);
}

// Round 8
// 229.434 us; speedup vs baseline: 1.0766x; 1.0766x over previous
//
#include <hip/hip_runtime.h>
#include <stdint.h>

#define B_ 2
#define S_ 2048
#define D_ 1024
#define H_ 16
#define DH_ 64
#define M_ 4096  // B_*S_

typedef unsigned short u16;
typedef unsigned int u32;
typedef short mfma_elem_t;
typedef mfma_elem_t bfrag8 __attribute__((ext_vector_type(8)));
typedef float floatx4 __attribute__((ext_vector_type(4)));

__device__ __forceinline__ u16 f2bf(float f) {
  unsigned u = __float_as_uint(f);
  u += 0x7fff + ((u >> 16) & 1);  // RNE
  return (u16)(u >> 16);
}

// pack two positive floats to packed bf16 (round-half-up)
__device__ __forceinline__ u32 pack_bf16(float a, float b) {
  u32 ua = __float_as_uint(a) + 0x8000u;
  u32 ub = __float_as_uint(b) + 0x8000u;
#if __has_builtin(__builtin_amdgcn_perm)
  return __builtin_amdgcn_perm(ub, ua, 0x07060302u);
#else
  return (ua >> 16) | (ub & 0xffff0000u);
#endif
}

__device__ __forceinline__ void gl_lds16(const void* g, void* l) {
  __builtin_amdgcn_global_load_lds(
      (__attribute__((address_space(1))) void*)(g),
      (__attribute__((address_space(3))) void*)(l), 16, 0, 0);
}

// ---------------- convert inputs fp32 -> bf16 ----------------
__global__ __launch_bounds__(256) void k_convert_x(
    const float* __restrict__ q, const float* __restrict__ k, const float* __restrict__ v,
    u16* __restrict__ xq, u16* __restrict__ xk, u16* __restrict__ xv) {
  const float* src = blockIdx.z == 0 ? q : (blockIdx.z == 1 ? k : v);
  u16* dst = blockIdx.z == 0 ? xq : (blockIdx.z == 1 ? xk : xv);
  int i = (blockIdx.x * 256 + threadIdx.x) * 4;
  float4 f = *(const float4*)(src + i);
  ushort4 o;
  o.x = f2bf(f.x); o.y = f2bf(f.y); o.z = f2bf(f.z); o.w = f2bf(f.w);
  *(ushort4*)(dst + i) = o;
}

// ---------------- convert + transpose W fp32[1024][1024] -> bf16 W^T ----------------
__global__ __launch_bounds__(256) void k_convert_w(
    const float* __restrict__ wq, const float* __restrict__ wk,
    const float* __restrict__ wv, const float* __restrict__ wo,
    u16* __restrict__ tq, u16* __restrict__ tk, u16* __restrict__ tv, u16* __restrict__ to_) {
  const int gz = blockIdx.z;
  const float* w = gz == 0 ? wq : gz == 1 ? wk : gz == 2 ? wv : wo;
  u16* t = gz == 0 ? tq : gz == 1 ? tk : gz == 2 ? tv : to_;
  __shared__ float tile[32][33];
  int r0 = blockIdx.y * 32, c0 = blockIdx.x * 32;
  int tx = threadIdx.x, ty = threadIdx.y;
#pragma unroll
  for (int i = 0; i < 4; i++) {
    int r = ty + i * 8;
    tile[r][tx] = w[(size_t)(r0 + r) * D_ + c0 + tx];
  }
  __syncthreads();
#pragma unroll
  for (int i = 0; i < 4; i++) {
    int r = ty + i * 8;
    t[(size_t)(c0 + r) * D_ + r0 + tx] = f2bf(tile[tx][r]);
  }
}

// ---------------- fused QKV projection GEMM (dbuf, 1 barrier/iter) ----------------
// Q out scaled by 0.125*log2e (folded softmax scale); Q,K out: [B,H,S,DH];
// V out: [B,H,DH,S] (transposed in epilogue)
__global__ __launch_bounds__(256, 3) void k_gemm_qkv(
    const u16* __restrict__ xq, const u16* __restrict__ xk, const u16* __restrict__ xv,
    const u16* __restrict__ wtq, const u16* __restrict__ wtk, const u16* __restrict__ wtv,
    const float* __restrict__ bq, const float* __restrict__ bk, const float* __restrict__ bv,
    u16* __restrict__ oq, u16* __restrict__ ok, u16* __restrict__ ovt) {
  const int gz = blockIdx.z;
  const u16* X = gz == 0 ? xq : gz == 1 ? xk : xv;
  const u16* WT = gz == 0 ? wtq : gz == 1 ? wtk : wtv;
  const float* bias = gz == 0 ? bq : gz == 1 ? bk : bv;
  u16* outsd = gz == 0 ? oq : ok;
  const float qscale = gz == 0 ? 0.125f * 1.4426950408889634f : 1.0f;

  __shared__ u16 sbuf[2][8192];

  const int t = threadIdx.x;
  const int w = t >> 6, lane = t & 63, l15 = lane & 15, quad = lane >> 4;
  const int wm = (w >> 1) * 64, wn = (w & 1) * 64;
  const int m0 = blockIdx.y * 128, n0 = blockIdx.x * 128;

  floatx4 acc[4][4];
  floatx4 zero = {0.f, 0.f, 0.f, 0.f};
#pragma unroll
  for (int mt = 0; mt < 4; mt++)
#pragma unroll
    for (int nt = 0; nt < 4; nt++) acc[mt][nt] = zero;

  auto stage = [&](int kt, int b) {
    int k0 = kt * 32;
#pragma unroll
    for (int i = 0; i < 2; i++) {
      int chunk = i * 256 + t;
      gl_lds16(X + (size_t)(m0 + (chunk >> 2)) * D_ + k0 + (chunk & 3) * 8,
               sbuf[b] + i * 2048 + w * 512);
      gl_lds16(WT + (size_t)(n0 + (chunk >> 2)) * D_ + k0 + (chunk & 3) * 8,
               sbuf[b] + 4096 + i * 2048 + w * 512);
    }
  };

  stage(0, 0);
  for (int kt = 0; kt < 32; kt++) {
    __syncthreads();
    if (kt < 31) stage(kt + 1, (kt + 1) & 1);
    const u16* As = sbuf[kt & 1];
    const u16* Bs = sbuf[kt & 1] + 4096;
    bfrag8 af[4], bf[4];
#pragma unroll
    for (int mt = 0; mt < 4; mt++)
      af[mt] = *(const bfrag8*)(As + (wm + mt * 16 + l15) * 32 + quad * 8);
#pragma unroll
    for (int nt = 0; nt < 4; nt++)
      bf[nt] = *(const bfrag8*)(Bs + (wn + nt * 16 + l15) * 32 + quad * 8);
#pragma unroll
    for (int mt = 0; mt < 4; mt++)
#pragma unroll
      for (int nt = 0; nt < 4; nt++)
        acc[mt][nt] = __builtin_amdgcn_mfma_f32_16x16x32_bf16(af[mt], bf[nt], acc[mt][nt], 0, 0, 0);
  }

  if (gz < 2) {
#pragma unroll
    for (int mt = 0; mt < 4; mt++)
#pragma unroll
      for (int nt = 0; nt < 4; nt++) {
        int Nc = n0 + wn + nt * 16 + l15;
        float bv_ = bias[Nc];
        int hh = Nc >> 6, dh = Nc & 63;
#pragma unroll
        for (int r = 0; r < 4; r++) {
          int Mr = m0 + wm + mt * 16 + quad * 4 + r;
          int bb = Mr >> 11, ss = Mr & 2047;
          outsd[((size_t)(bb * H_ + hh) * S_ + ss) * DH_ + dh] =
              f2bf((acc[mt][nt][r] + bv_) * qscale);
        }
      }
  } else {
#pragma unroll
    for (int mt = 0; mt < 4; mt++)
#pragma unroll
      for (int nt = 0; nt < 4; nt++) {
        int Nc = n0 + wn + nt * 16 + l15;
        float bv_ = bias[Nc];
        int hh = Nc >> 6, dh = Nc & 63;
        int Mr0 = m0 + wm + mt * 16 + quad * 4;
        int bb = Mr0 >> 11, ss0 = Mr0 & 2047;
        ushort4 o;
        o.x = f2bf(acc[mt][nt][0] + bv_);
        o.y = f2bf(acc[mt][nt][1] + bv_);
        o.z = f2bf(acc[mt][nt][2] + bv_);
        o.w = f2bf(acc[mt][nt][3] + bv_);
        *(ushort4*)(ovt + ((size_t)(bb * H_ + hh) * DH_ + dh) * S_ + ss0) = o;
      }
  }
}

// ---------------- final GEMM (dbuf): out fp32 = O[4096,1024] * Wo + bo ----------------
__global__ __launch_bounds__(256, 3) void k_gemm_final(
    const u16* __restrict__ X, const u16* __restrict__ WT,
    const float* __restrict__ bias, float* __restrict__ out) {
  __shared__ u16 sbuf[2][8192];
  const int t = threadIdx.x;
  const int w = t >> 6, lane = t & 63, l15 = lane & 15, quad = lane >> 4;
  const int wm = (w >> 1) * 64, wn = (w & 1) * 64;
  const int m0 = blockIdx.y * 128, n0 = blockIdx.x * 128;

  floatx4 acc[4][4];
  floatx4 zero = {0.f, 0.f, 0.f, 0.f};
#pragma unroll
  for (int mt = 0; mt < 4; mt++)
#pragma unroll
    for (int nt = 0; nt < 4; nt++) acc[mt][nt] = zero;

  auto stage = [&](int kt, int b) {
    int k0 = kt * 32;
#pragma unroll
    for (int i = 0; i < 2; i++) {
      int chunk = i * 256 + t;
      gl_lds16(X + (size_t)(m0 + (chunk >> 2)) * D_ + k0 + (chunk & 3) * 8,
               sbuf[b] + i * 2048 + w * 512);
      gl_lds16(WT + (size_t)(n0 + (chunk >> 2)) * D_ + k0 + (chunk & 3) * 8,
               sbuf[b] + 4096 + i * 2048 + w * 512);
    }
  };

  stage(0, 0);
  for (int kt = 0; kt < 32; kt++) {
    __syncthreads();
    if (kt < 31) stage(kt + 1, (kt + 1) & 1);
    const u16* As = sbuf[kt & 1];
    const u16* Bs = sbuf[kt & 1] + 4096;
    bfrag8 af[4], bf[4];
#pragma unroll
    for (int mt = 0; mt < 4; mt++)
      af[mt] = *(const bfrag8*)(As + (wm + mt * 16 + l15) * 32 + quad * 8);
#pragma unroll
    for (int nt = 0; nt < 4; nt++)
      bf[nt] = *(const bfrag8*)(Bs + (wn + nt * 16 + l15) * 32 + quad * 8);
#pragma unroll
    for (int mt = 0; mt < 4; mt++)
#pragma unroll
      for (int nt = 0; nt < 4; nt++)
        acc[mt][nt] = __builtin_amdgcn_mfma_f32_16x16x32_bf16(af[mt], bf[nt], acc[mt][nt], 0, 0, 0);
  }
#pragma unroll
  for (int mt = 0; mt < 4; mt++)
#pragma unroll
    for (int nt = 0; nt < 4; nt++) {
      int Nc = n0 + wn + nt * 16 + l15;
      float bv_ = bias[Nc];
#pragma unroll
      for (int r = 0; r < 4; r++) {
        int Mr = m0 + wm + mt * 16 + quad * 4 + r;
        out[(size_t)Mr * D_ + Nc] = acc[mt][nt][r] + bv_;
      }
    }
}

// ---------------- flash attention v6b: v3 shape + kv-split-2 ----------------
// Grid (16 q-tiles, 16 h, 4 = split*2 + b). Block: 4 waves x (32q x kv64-tile),
// dbuf staging (1 barrier/iter), 16 iters over the block's 1024-kv half.
// LDS = 40960 B: K/V dbuf 2x16KB + P 4x2KB ([32 q][32 kv] u16, XOR-swizzled
// phys_col = col ^ ((l15&6)<<2): conflict-free writes AND b128 reads).
// launch_bounds (256,3): soft VGPR cap; 4 blocks/CU come from LDS+actual VGPRs.
// Output: UNNORMALIZED O partial (bf16) + l partial (fp32) per split -> k_combine.
__global__ __launch_bounds__(256, 3) void k_attn(
    const u16* __restrict__ Q, const u16* __restrict__ K,
    const u16* __restrict__ Vt, u16* __restrict__ Opart, float* __restrict__ Lpart) {
  __shared__ u16 lds[20480];  // 40 KB

  const int t = threadIdx.x, w = t >> 6, lane = t & 63, l15 = lane & 15, quad = lane >> 4;
  const int split = blockIdx.z >> 1, b = blockIdx.z & 1;
  const int bh = b * H_ + blockIdx.y;
  const int q0 = blockIdx.x * 128;
  const int kvbase = split * 1024;
  const u16* Qb = Q + (size_t)bh * S_ * DH_;
  const u16* Kb = K + (size_t)bh * S_ * DH_;
  const u16* Vb = Vt + (size_t)bh * DH_ * S_;
  u16* Pw = lds + 16384 + w * 1024;
  const int swz = (l15 & 6) << 2;  // column-unit XOR swizzle

  bfrag8 qf[2][2];  // B-operand [n=q][k=dh], loaded once from global (Q pre-scaled)
#pragma unroll
  for (int mt = 0; mt < 2; mt++)
#pragma unroll
    for (int ks = 0; ks < 2; ks++)
      qf[mt][ks] = *(const bfrag8*)(Qb + (size_t)(q0 + w * 32 + mt * 16 + l15) * DH_ + ks * 32 + quad * 8);

  auto stage = [&](int kv0, int bb) {
    u16* Kbuf = lds + bb * 8192;
    u16* Vbuf = lds + bb * 8192 + 4096;
#pragma unroll
    for (int ks = 0; ks < 2; ks++)
      gl_lds16(Kb + (size_t)(kv0 + (t >> 2)) * DH_ + ks * 32 + (t & 3) * 8,
               Kbuf + ks * 2048 + w * 512);
#pragma unroll
    for (int ksp = 0; ksp < 2; ksp++)
      gl_lds16(Vb + (size_t)(t >> 2) * S_ + kv0 + ksp * 32 + (t & 3) * 8,
               Vbuf + ksp * 2048 + w * 512);
  };

  floatx4 oacc[2][4];
  float lrow[2] = {0.f, 0.f};
  floatx4 zero = {0.f, 0.f, 0.f, 0.f};
#pragma unroll
  for (int mt = 0; mt < 2; mt++)
#pragma unroll
    for (int dt = 0; dt < 4; dt++) oacc[mt][dt] = zero;

  stage(kvbase, 0);
  for (int kt = 0; kt < 16; kt++) {
    __syncthreads();  // drains stage(kt); all waves done reading buf[(kt+1)&1]
    if (kt < 15) stage(kvbase + (kt + 1) * 64, (kt + 1) & 1);
    const u16* Kbuf = lds + (kt & 1) * 8192;
    const u16* Vbuf = lds + (kt & 1) * 8192 + 4096;

    // S^T tiles: D[m=kv][n=q] = mfma(A=K-frag, B=Q-frag)
    floatx4 sacc[2][4];
#pragma unroll
    for (int nt = 0; nt < 4; nt++) {
      bfrag8 kf0 = *(const bfrag8*)(Kbuf + (nt * 16 + l15) * 32 + quad * 8);
      bfrag8 kf1 = *(const bfrag8*)(Kbuf + 2048 + (nt * 16 + l15) * 32 + quad * 8);
#pragma unroll
      for (int mt = 0; mt < 2; mt++) {
        floatx4 s0 = __builtin_amdgcn_mfma_f32_16x16x32_bf16(kf0, qf[mt][0], zero, 0, 0, 0);
        sacc[mt][nt] = __builtin_amdgcn_mfma_f32_16x16x32_bf16(kf1, qf[mt][1], s0, 0, 0, 0);
      }
    }

    // per 32-kv chunk: exp2, pack, swizzled P write, PV (wave-private, no barrier)
#pragma unroll
    for (int c = 0; c < 2; c++) {
#pragma unroll
      for (int j = 0; j < 2; j++) {
        const int nt = c * 2 + j;
#pragma unroll
        for (int mt = 0; mt < 2; mt++) {
          float p0 = __builtin_amdgcn_exp2f(sacc[mt][nt][0]);
          float p1 = __builtin_amdgcn_exp2f(sacc[mt][nt][1]);
          float p2 = __builtin_amdgcn_exp2f(sacc[mt][nt][2]);
          float p3 = __builtin_amdgcn_exp2f(sacc[mt][nt][3]);
          lrow[mt] += (p0 + p1) + (p2 + p3);
          uint2 pd;
          pd.x = pack_bf16(p0, p1);
          pd.y = pack_bf16(p2, p3);
          *(uint2*)(Pw + (mt * 16 + l15) * 32 + ((j * 16 + quad * 4) ^ swz)) = pd;
        }
      }
      bfrag8 pf[2];
#pragma unroll
      for (int mt = 0; mt < 2; mt++)
        pf[mt] = *(const bfrag8*)(Pw + (mt * 16 + l15) * 32 + ((quad * 8) ^ swz));
#pragma unroll
      for (int dt = 0; dt < 4; dt++) {
        bfrag8 vf = *(const bfrag8*)(Vbuf + c * 2048 + (dt * 16 + l15) * 32 + quad * 8);
        oacc[0][dt] = __builtin_amdgcn_mfma_f32_16x16x32_bf16(vf, pf[0], oacc[0][dt], 0, 0, 0);
        oacc[1][dt] = __builtin_amdgcn_mfma_f32_16x16x32_bf16(vf, pf[1], oacc[1][dt], 0, 0, 0);
      }
    }
  }

  // epilogue: quad-reduce l; store UNNORMALIZED O partial (bf16) + l (fp32)
#pragma unroll
  for (int mt = 0; mt < 2; mt++) {
    float l = lrow[mt];
    l += __shfl_xor(l, 16, 64);
    l += __shfl_xor(l, 32, 64);
    int qrow = q0 + w * 32 + mt * 16 + l15;
    size_t base = ((size_t)(split * 32 + bh) * S_ + qrow) * DH_;
#pragma unroll
    for (int dt = 0; dt < 4; dt++) {
      ushort4 o;
      o.x = f2bf(oacc[mt][dt][0]);
      o.y = f2bf(oacc[mt][dt][1]);
      o.z = f2bf(oacc[mt][dt][2]);
      o.w = f2bf(oacc[mt][dt][3]);
      *(ushort4*)(Opart + base + dt * 16 + quad * 4) = o;
    }
    if (quad == 0) Lpart[(size_t)(split * 32 + bh) * S_ + qrow] = l;
  }
}

// ---------------- combine kv-split partials: O = (P0+P1)/(l0+l1), bf16 out ----------------
__global__ __launch_bounds__(256) void k_combine(
    const u16* __restrict__ Opart, const float* __restrict__ Lpart, u16* __restrict__ Obuf) {
  int idx = (blockIdx.x * 256 + threadIdx.x) * 8;  // over 4096*1024 elems
  int col = idx & 1023;            // h*64 + dh
  int row = idx >> 10;             // b*2048 + s
  int bb = row >> 11, s = row & 2047;
  int h = col >> 6, dh = col & 63;
  int bh = bb * H_ + h;
  size_t p0 = ((size_t)bh * S_ + s) * DH_ + dh;
  size_t p1 = ((size_t)(32 + bh) * S_ + s) * DH_ + dh;
  float rinv = 1.0f / (Lpart[(size_t)bh * S_ + s] + Lpart[(size_t)(32 + bh) * S_ + s]);
  uint4 a = *(const uint4*)(Opart + p0);
  uint4 c = *(const uint4*)(Opart + p1);
  u32 av[4] = {a.x, a.y, a.z, a.w};
  u32 cv[4] = {c.x, c.y, c.z, c.w};
  u16 res[8];
#pragma unroll
  for (int i = 0; i < 4; i++) {
    float alo = __uint_as_float(av[i] << 16), ahi = __uint_as_float(av[i] & 0xffff0000u);
    float clo = __uint_as_float(cv[i] << 16), chi = __uint_as_float(cv[i] & 0xffff0000u);
    res[i * 2] = f2bf((alo + clo) * rinv);
    res[i * 2 + 1] = f2bf((ahi + chi) * rinv);
  }
  uint4 out;
  out.x = (u32)res[0] | ((u32)res[1] << 16);
  out.y = (u32)res[2] | ((u32)res[3] << 16);
  out.z = (u32)res[4] | ((u32)res[5] << 16);
  out.w = (u32)res[6] | ((u32)res[7] << 16);
  *(uint4*)(Obuf + idx) = out;
}

// ---------------- launch ----------------
extern "C" void kernel_launch(void* const* d_in, const int* in_sizes, int n_in,
                              void* d_out, int out_size, void* d_ws, size_t ws_size,
                              hipStream_t stream) {
  const float* queries = (const float*)d_in[0];
  const float* keys = (const float*)d_in[1];
  const float* values = (const float*)d_in[2];
  const float* Wq = (const float*)d_in[3];
  const float* bq = (const float*)d_in[4];
  const float* Wk = (const float*)d_in[5];
  const float* bk = (const float*)d_in[6];
  const float* Wv = (const float*)d_in[7];
  const float* bv = (const float*)d_in[8];
  const float* Wo = (const float*)d_in[9];
  const float* bo = (const float*)d_in[10];

  const size_t NXB = (size_t)M_ * D_ * 2;  // 8 MB
  const size_t WB = (size_t)D_ * D_ * 2;   // 2 MB
  if (ws_size < 7 * NXB + 4 * WB) return;  // 64 MB

  char* ws = (char*)d_ws;
  u16* Xq = (u16*)(ws);
  u16* Xk = (u16*)(ws + NXB);
  u16* Xv = (u16*)(ws + 2 * NXB);
  u16* WqT = (u16*)(ws + 3 * NXB);
  u16* WkT = (u16*)(ws + 3 * NXB + WB);
  u16* WvT = (u16*)(ws + 3 * NXB + 2 * WB);
  u16* WoT = (u16*)(ws + 3 * NXB + 3 * WB);
  char* ws2 = ws + 3 * NXB + 4 * WB;
  u16* Qhs = (u16*)(ws2);
  u16* Khs = (u16*)(ws2 + NXB);
  u16* VtB = (u16*)(ws2 + 2 * NXB);
  u16* Obuf = (u16*)(ws2 + 3 * NXB);
  // kv-split partials alias the dead Xq/Xk/Xv region (consumed by k_gemm_qkv
  // before k_attn runs; same-stream ordering): Opart 16.8 MB @0, Lpart @18 MB.
  u16* Opart = (u16*)(ws);
  float* Lpart = (float*)(ws + 18 * 1024 * 1024);
  float* outp = (float*)d_out;

  k_convert_x<<<dim3(4096, 1, 3), 256, 0, stream>>>(queries, keys, values, Xq, Xk, Xv);
  k_convert_w<<<dim3(32, 32, 4), dim3(32, 8), 0, stream>>>(Wq, Wk, Wv, Wo, WqT, WkT, WvT, WoT);
  k_gemm_qkv<<<dim3(8, 32, 3), 256, 0, stream>>>(Xq, Xk, Xv, WqT, WkT, WvT, bq, bk, bv, Qhs, Khs, VtB);
  k_attn<<<dim3(16, 16, 4), 256, 0, stream>>>(Qhs, Khs, VtB, Opart, Lpart);
  k_combine<<<dim3(2048), 256, 0, stream>>>(Opart, Lpart, Obuf);
  k_gemm_final<<<dim3(8, 32), 256, 0, stream>>>(Obuf, WoT, bo, outp);
}